// Round 6
// baseline (112.995 us; speedup 1.0000x reference)
//
#include <hip/hip_runtime.h>
#include <hip/hip_bf16.h>
#include <cstdint>

// Problem constants (reference: B=4, K=32, S=1024, H=512, FFN=2304)
#define BB 4
#define KK 32
#define SS 1024
#define HH 512
#define FFN 2304
#define M_PAIRS (BB * KK * KK)   // 4096
#define K1 (3 * HH)              // 1536

using bf16 = __hip_bfloat16;
using f32x4 = __attribute__((ext_vector_type(4))) float;
using bf16x8 = __attribute__((ext_vector_type(8))) short;

struct bf16x2 { bf16 x, y; };

__device__ __forceinline__ float bf2f(bf16 v) { return __bfloat162float(v); }

// ---------------------------------------------------------------------------
// Transpose + f32->bf16 cast: in[R][C] f32 -> out[C][R] bf16. 32x32 tiles.
// ---------------------------------------------------------------------------
__global__ __launch_bounds__(256) void transpose_to_bf16(
    const float* __restrict__ in, bf16* __restrict__ out, int R, int C)
{
    __shared__ float tile[32][33];
    int bc = blockIdx.x * 32;
    int br = blockIdx.y * 32;
    int tx = threadIdx.x & 31;
    int ty = threadIdx.x >> 5;
#pragma unroll
    for (int i = 0; i < 32; i += 8)
        tile[ty + i][tx] = in[(size_t)(br + ty + i) * C + bc + tx];
    __syncthreads();
#pragma unroll
    for (int i = 0; i < 32; i += 8)
        out[(size_t)(bc + ty + i) * R + br + tx] = __float2bfloat16(tile[tx][ty + i]);
}

// ---------------------------------------------------------------------------
// Sparse range-max table, every-other level: window sizes q = 4,16,64,256.
// ---------------------------------------------------------------------------
#define TBL_LVL_STRIDE ((size_t)BB * SS * HH)

__global__ __launch_bounds__(256) void build_table_l0(
    const float* __restrict__ tok, bf16* __restrict__ tbl0)
{
    int bt = blockIdx.x;
    int b = bt >> 10, t = bt & 1023;
    int h0 = threadIdx.x * 2;
    const float* base = tok + (size_t)b * SS * HH;
    float m0 = -INFINITY, m1 = -INFINITY;
#pragma unroll
    for (int j = 0; j < 4; ++j) {
        int tt = min(t + j, SS - 1);
        float2 v = *(const float2*)(base + (size_t)tt * HH + h0);
        m0 = fmaxf(m0, v.x);
        m1 = fmaxf(m1, v.y);
    }
    bf16x2 o;
    o.x = __float2bfloat16(m0);
    o.y = __float2bfloat16(m1);
    *(bf16x2*)(tbl0 + (size_t)bt * HH + h0) = o;
}

__global__ __launch_bounds__(256) void build_table_next(
    const bf16* __restrict__ prev, bf16* __restrict__ out, int qp)
{
    int bt = blockIdx.x;
    int b = bt >> 10, t = bt & 1023;
    int h0 = threadIdx.x * 2;
    const bf16* base = prev + (size_t)b * SS * HH;
    float m0 = -INFINITY, m1 = -INFINITY;
#pragma unroll
    for (int j = 0; j < 4; ++j) {
        int tt = min(t + j * qp, SS - qp);
        bf16x2 v = *(const bf16x2*)(base + (size_t)tt * HH + h0);
        m0 = fmaxf(m0, bf2f(v.x));
        m1 = fmaxf(m1, bf2f(v.y));
    }
    bf16x2 o;
    o.x = __float2bfloat16(m0);
    o.y = __float2bfloat16(m1);
    *(bf16x2*)(out + (size_t)bt * HH + h0) = o;
}

// ---------------------------------------------------------------------------
// build_rel: one block per pair (b,i,j).
// ---------------------------------------------------------------------------
__global__ __launch_bounds__(256) void build_rel(
    const float* __restrict__ cand,
    const float* __restrict__ tok,
    const int* __restrict__ ids,
    const bf16* __restrict__ tbl,
    bf16* __restrict__ rel)
{
    int pair = blockIdx.x;
    int b = pair >> 10;
    int i = (pair >> 5) & 31;
    int j = pair & 31;
    int t = threadIdx.x;

    int si = ids[((b * KK + i) << 1)];
    int ei = ids[((b * KK + i) << 1) + 1];
    int sj = ids[((b * KK + j) << 1)];
    int ej = ids[((b * KK + j) << 1) + 1];
    int me = min(ei, ej);
    int ms = max(si, sj);

    const float* head = cand + ((size_t)b * KK + i) * HH;
    const float* tail = cand + ((size_t)b * KK + j) * HH;
    bf16* outp = rel + (size_t)pair * K1;

#pragma unroll
    for (int h = t; h < HH; h += 256) {
        outp[h] = __float2bfloat16(head[h]);
        outp[HH + h] = __float2bfloat16(tail[h]);
    }

    bf16* ctx = outp + 2 * HH;
    if (me < ms) {
        int L = ms - me;
        if (L < 4) {
            float m0 = -INFINITY, m1 = -INFINITY;
            const float* tb = tok + (size_t)b * SS * HH;
            for (int tt = me; tt < ms; ++tt) {
                const float* row = tb + (size_t)tt * HH;
                m0 = fmaxf(m0, row[t]);
                m1 = fmaxf(m1, row[t + 256]);
            }
            ctx[t] = __float2bfloat16(m0);
            ctx[t + 256] = __float2bfloat16(m1);
        } else {
            int lvl = (L < 16) ? 0 : (L < 64) ? 1 : (L < 256) ? 2 : 3;
            int q = 4 << (2 * lvl);
            const bf16* base = tbl + (size_t)lvl * TBL_LVL_STRIDE + (size_t)b * SS * HH;
            float m0 = -INFINITY, m1 = -INFINITY;
#pragma unroll
            for (int jj = 0; jj < 4; ++jj) {
                int p = min(me + jj * q, ms - q);
                const bf16* row = base + (size_t)p * HH;
                m0 = fmaxf(m0, bf2f(row[t]));
                m1 = fmaxf(m1, bf2f(row[t + 256]));
            }
            ctx[t] = __float2bfloat16(m0);
            ctx[t + 256] = __float2bfloat16(m1);
        }
    } else {
        ctx[t] = __float2bfloat16(head[t]);
        ctx[t + 256] = __float2bfloat16(head[t + 256]);
    }
}

// ---------------------------------------------------------------------------
__device__ __forceinline__ void gload_lds16(const bf16* g, bf16* l)
{
    __builtin_amdgcn_global_load_lds(
        (const __attribute__((address_space(1))) unsigned int*)g,
        (__attribute__((address_space(3))) unsigned int*)l,
        16, 0, 0);
}

#define BAR() asm volatile("s_barrier" ::: "memory")
#define VMCNT0() asm volatile("s_waitcnt vmcnt(0)" ::: "memory")

// ---------------------------------------------------------------------------
// gemm_ad: A-DIRECT GEMM. Block 128 x (NF*16), 2 waves; wave tile = 64 x BN.
// A-fragments load straight from global (L2/L3-resident) into registers,
// double-buffered one K-tile ahead -> no A traffic through LDS at all.
// B staged via global_load_lds into 24.6KB double-buffered LDS with the
// verified 16B-chunk XOR swizzle (both sides, rule #21). Per-tile vmcnt(0)
// boundary is ~free: the prefetch had a full compute phase to land.
// MODE 0: GEMM1 grid 32x24=768 (3/CU), 2-D XCD chunks (8 x [8bm x 12bn])
//         so each XCD's working set (A 3.1MB + B 3.5MB) is ~L2-sized.
// MODE 1: linear chunked XCD swizzle + split-K via nper.
// ---------------------------------------------------------------------------
template <int NF, bool RELU, bool OUT_BF16, bool ADD_BIAS, int MODE>
__global__ __launch_bounds__(128, 2) void gemm_ad(
    const bf16* __restrict__ A,    // [M_PAIRS][lda]
    const bf16* __restrict__ BT,   // [*][ldb]
    const float* __restrict__ bias,
    void* __restrict__ Cout,       // [M_PAIRS][ldc] per split
    int lda, int ldb, int NT, int nbn, int nper, int ldc)
{
    constexpr int BN_ = NF * 16;
    __shared__ __align__(16) bf16 ldsB[2][BN_ * 64];

    int bm, bn, s;
    if (MODE == 0) {   // 8 chunks (one per XCD, blockIdx%8 round-robin) of 8x12
        int x = blockIdx.x & 7, k = blockIdx.x >> 3;   // k in 0..95
        bm = (x & 3) * 8 + (k & 7);                    // 0..31
        bn = (x >> 2) * 12 + (k >> 3);                 // 0..23
        s = 0;
    } else {
        int cpx = gridDim.x >> 3;
        int wg = (blockIdx.x & 7) * cpx + (blockIdx.x >> 3);
        s = wg / nper;
        int rem = wg - s * nper;
        bm = rem / nbn;
        bn = rem - bm * nbn;
    }
    const int row0 = bm * 128;
    const int col0 = bn * BN_;

    const bf16* As = A  + (size_t)s * NT * 64;   // K-split offset
    const bf16* Bs = BT + (size_t)s * NT * 64;

    const int tid = threadIdx.x;
    const int w = tid >> 6, l = tid & 63;        // 2 waves: wave w owns rows w*64..+63

    // staging lane constants (pre-swizzled source chunk; linear LDS dest)
    const int lr  = l >> 3;                      // 0..7
    const int lch = (l & 7) ^ lr;
    // ds_read swizzled offsets (read row = n*16 + l15 -> key row&7 == l&7)
    const int l15 = l & 15;
    const int sw0 = (((l >> 4)    ) ^ (l & 7)) * 16;
    const int sw1 = (((l >> 4) + 4) ^ (l & 7)) * 16;

    auto stageB = [&](int t, int sb) {
        const bf16* g = Bs + (size_t)(col0 + w * (NF * 8) + lr) * ldb + t * 64 + lch * 8;
        bf16* d = &ldsB[sb][(w * (NF * 8)) * 64];
#pragma unroll
        for (int j = 0; j < NF; ++j)
            gload_lds16(g + (size_t)(j * 8) * ldb, d + j * 512);
    };

    // A-fragment direct load: lane l -> row m*16+(l&15), k-chunk (l>>4)*8.
    // One instr = 16 rows x 64B contiguous: clean 1KB L2 transaction.
    auto loadA = [&](bf16x8 (&af)[4][2], int t) {
#pragma unroll
        for (int m = 0; m < 4; ++m) {
            const bf16* p = As + (size_t)(row0 + w * 64 + m * 16 + l15) * lda
                            + t * 64 + (l >> 4) * 8;
            af[m][0] = *(const bf16x8*)p;
            af[m][1] = *(const bf16x8*)(p + 32);
        }
    };

    f32x4 acc[4][NF] = {};

    auto comp = [&](bf16x8 (&af)[4][2], int sb) {
        const char* Bb = (const char*)&ldsB[sb][0] + l15 * 128;
        bf16x8 bfr[NF][2];
#pragma unroll
        for (int n = 0; n < NF; ++n) {
            const char* p = Bb + n * 2048;
            bfr[n][0] = *(const bf16x8*)(p + sw0);
            bfr[n][1] = *(const bf16x8*)(p + sw1);
        }
        __builtin_amdgcn_s_setprio(1);
#pragma unroll
        for (int m = 0; m < 4; ++m)
#pragma unroll
            for (int n = 0; n < NF; ++n)
#pragma unroll
                for (int kk = 0; kk < 2; ++kk)
                    acc[m][n] = __builtin_amdgcn_mfma_f32_16x16x32_bf16(
                        af[m][kk], bfr[n][kk], acc[m][n], 0, 0, 0);
        __builtin_amdgcn_s_setprio(0);
    };

    bf16x8 afA[4][2], afB[4][2];

    loadA(afA, 0);
    stageB(0, 0);
    VMCNT0();
    BAR();

    for (int t = 0; t < NT; t += 2) {           // NT even (24 / 18)
        if (t + 1 < NT) { stageB(t + 1, 1); loadA(afB, t + 1); }
        comp(afA, 0);
        VMCNT0();
        BAR();
        if (t + 2 < NT) { stageB(t + 2, 0); loadA(afA, t + 2); }
        comp(afB, 1);
        VMCNT0();
        BAR();
    }

    // epilogue. C/D: col=lane&15, row=(lane>>4)*4+q
    const int crow = (l >> 4) * 4;
    char* outBase = (char*)Cout + (size_t)s * M_PAIRS * ldc * (OUT_BF16 ? 2 : 4);
#pragma unroll
    for (int m = 0; m < 4; ++m) {
        int row = row0 + w * 64 + m * 16 + crow;
#pragma unroll
        for (int n = 0; n < NF; ++n) {
            int col = col0 + n * 16 + l15;
            float bv = ADD_BIAS ? bias[col] : 0.f;
#pragma unroll
            for (int q = 0; q < 4; ++q) {
                float v = acc[m][n][q] + bv;
                if (RELU) v = fmaxf(v, 0.f);
                size_t idx = (size_t)(row + q) * ldc + col;
                if (OUT_BF16)
                    ((bf16*)outBase)[idx] = __float2bfloat16(v);
                else
                    ((float*)outBase)[idx] = v;
            }
        }
    }
}

// ---------------------------------------------------------------------------
// reduce: out = P0 + P1 + bias  (f32, vectorized float4)
// ---------------------------------------------------------------------------
__global__ __launch_bounds__(256) void reduce_bias(
    const float* __restrict__ P, const float* __restrict__ b2,
    float* __restrict__ out)
{
    int idx = blockIdx.x * 256 + threadIdx.x;        // float4 index
    const float4* p0 = (const float4*)P;
    const float4* p1 = (const float4*)(P + (size_t)M_PAIRS * HH);
    float4 a = p0[idx];
    float4 b = p1[idx];
    float4 bv = ((const float4*)b2)[idx & 127];      // 512 cols = 128 float4
    float4 r;
    r.x = a.x + b.x + bv.x;
    r.y = a.y + b.y + bv.y;
    r.z = a.z + b.z + bv.z;
    r.w = a.w + b.w + bv.w;
    ((float4*)out)[idx] = r;
}

// ---------------------------------------------------------------------------
extern "C" void kernel_launch(void* const* d_in, const int* in_sizes, int n_in,
                              void* d_out, int out_size, void* d_ws, size_t ws_size,
                              hipStream_t stream)
{
    const float* cand = (const float*)d_in[0];
    const float* tok  = (const float*)d_in[1];
    const float* W1   = (const float*)d_in[2];
    const float* b1   = (const float*)d_in[3];
    const float* W2   = (const float*)d_in[4];
    const float* b2   = (const float*)d_in[5];
    const int*   ids  = (const int*)d_in[6];
    float* out = (float*)d_out;

    char* ws = (char*)d_ws;
    const size_t relB_sz = (size_t)M_PAIRS * K1 * 2;        // 12,582,912
    const size_t w1t_sz  = (size_t)FFN * K1 * 2;            //  7,077,888
    const size_t w2t_sz  = (size_t)HH * FFN * 2;            //  2,359,296
    bf16* relB = (bf16*)ws;
    bf16* W1T  = (bf16*)(ws + relB_sz);
    bf16* W2T  = (bf16*)(ws + relB_sz + w1t_sz);
    char* regionX = ws + relB_sz + w1t_sz + w2t_sz;
    bf16* tbl = (bf16*)regionX;   // 16 MB, dead after build_rel
    bf16* hid = (bf16*)regionX;   // 18.9 MB, written by GEMM1 afterwards
    // GEMM2 split-K partials: 2 x 4096 x 512 f32 = 16.78 MB, aliases
    // relB (12.6 MB) + W1T (7.1 MB) -- both dead after GEMM1. W2T/hid live.
    float* P = (float*)ws;

    // 1) weight transpose+cast
    transpose_to_bf16<<<dim3(FFN / 32, K1 / 32), 256, 0, stream>>>(W1, W1T, K1, FFN);
    transpose_to_bf16<<<dim3(HH / 32, FFN / 32), 256, 0, stream>>>(W2, W2T, FFN, HH);

    // 2) sparse range-max table: q = 4, 16, 64, 256
    build_table_l0<<<BB * SS, 256, 0, stream>>>(tok, tbl);
    build_table_next<<<BB * SS, 256, 0, stream>>>(tbl + 0 * TBL_LVL_STRIDE,
                                                  tbl + 1 * TBL_LVL_STRIDE, 4);
    build_table_next<<<BB * SS, 256, 0, stream>>>(tbl + 1 * TBL_LVL_STRIDE,
                                                  tbl + 2 * TBL_LVL_STRIDE, 16);
    build_table_next<<<BB * SS, 256, 0, stream>>>(tbl + 2 * TBL_LVL_STRIDE,
                                                  tbl + 3 * TBL_LVL_STRIDE, 64);

    // 3) build rel = [heads|tails|context] bf16
    build_rel<<<M_PAIRS, 256, 0, stream>>>(cand, tok, ids, tbl, relB);

    // 4) hid = relu(rel @ W1 + b1) -> bf16. A-direct, block 128x96,
    //    grid 32x24 = 768 = 3 blocks/CU uniform, 2-D XCD chunks.
    gemm_ad<6, true, true, true, 0><<<768, 128, 0, stream>>>(
        relB, W1T, b1, hid, K1, K1, /*NT=*/24, /*nbn=*/24, /*nper=*/768, FFN);

    // 5) P[s] = hid @ W2 (K-split 2, no bias) -> f32. A-direct, block 128x64,
    //    grid 2 x (32x8) = 512 = 2 blocks/CU.
    gemm_ad<4, false, false, false, 1><<<512, 128, 0, stream>>>(
        hid, W2T, nullptr, P, FFN, FFN, /*NT=*/18, /*nbn=*/8, /*nper=*/256, HH);

    // 6) out = P0 + P1 + b2
    reduce_bias<<<(M_PAIRS * HH / 4) / 256, 256, 0, stream>>>(P, b2, out);
}